// Round 1
// baseline (920.909 us; speedup 1.0000x reference)
//
#include <hip/hip_runtime.h>
#include <stdint.h>

#define B_ROWS 2048
#define D2_DIM 256
#define D_DIM 128
#define M_ITEMS 100000
#define BN_EPS_F 1e-5f
#define COS_EPS_F 1e-6f
#define LEAKY_F 0.01f

#define KB 32
#define TILE_R 128
#define TILE_I 128
#define SUPER 4

// ---------- kernel 1: h = item_feature @ W + b  (2048x256 @ 256x128) ----------
__global__ void k_gemm1(const float* __restrict__ A, const float* __restrict__ W,
                        const float* __restrict__ bias, float* __restrict__ h) {
  __shared__ float arow[D2_DIM];
  const int r = blockIdx.x;
  const int c = threadIdx.x;  // 128 threads
  arow[c] = A[r * D2_DIM + c];
  arow[c + 128] = A[r * D2_DIM + c + 128];
  __syncthreads();
  float acc = 0.f;
#pragma unroll 8
  for (int k = 0; k < D2_DIM; k++) acc = fmaf(arow[k], W[k * D_DIM + c], acc);
  h[r * D_DIM + c] = acc + bias[c];
}

// ---------- kernel 2: per-column mean/var -> scale/shift ----------
__global__ void k_bnstats(const float* __restrict__ h, const float* __restrict__ gamma,
                          const float* __restrict__ beta, float* __restrict__ scale,
                          float* __restrict__ shift) {
  const int c = blockIdx.x;   // 128 columns
  const int t = threadIdx.x;  // 256 threads
  double s = 0.0, sq = 0.0;
  for (int r = t; r < B_ROWS; r += 256) {
    double v = (double)h[r * D_DIM + c];
    s += v;
    sq += v * v;
  }
  __shared__ double ls[256], lq[256];
  ls[t] = s; lq[t] = sq;
  __syncthreads();
  for (int off = 128; off; off >>= 1) {
    if (t < off) { ls[t] += ls[t + off]; lq[t] += lq[t + off]; }
    __syncthreads();
  }
  if (t == 0) {
    double mean = ls[0] / (double)B_ROWS;
    double var = lq[0] / (double)B_ROWS - mean * mean;
    float sc = (float)((double)gamma[c] / sqrt(var + (double)BN_EPS_F));
    scale[c] = sc;
    shift[c] = beta[c] - (float)mean * sc;
  }
}

// ---------- kernel 3: uf = leaky(h*scale + shift) ----------
__global__ void k_norm(const float* __restrict__ h, const float* __restrict__ scale,
                       const float* __restrict__ shift, float* __restrict__ uf) {
  int i = blockIdx.x * blockDim.x + threadIdx.x;
  if (i >= B_ROWS * D_DIM) return;
  int c = i & (D_DIM - 1);
  float v = fmaf(h[i], scale[c], shift[c]);
  uf[i] = v >= 0.f ? v : LEAKY_F * v;
}

// ---------- kernel 4: init argmax keys ----------
__global__ void k_init(unsigned long long* __restrict__ keys) {
  int i = blockIdx.x * blockDim.x + threadIdx.x;
  if (i < B_ROWS) keys[i] = 0ull;
}

// ---------- kernel 5: fused scores GEMM + per-row argmax ----------
// block tile: 128 rows x 128 items, 8x8 per thread, K tiled by 32.
// Each block covers SUPER=4 item tiles (512 items), then one atomicMax/row.
__launch_bounds__(256, 2)
__global__ void k_scores(const float* __restrict__ uf, const float* __restrict__ items,
                         unsigned long long* __restrict__ keys) {
  __shared__ float As[KB][132];  // [k][row], padded stride
  __shared__ float Bs[KB][132];  // [k][item]
  const int tid = threadIdx.x;
  const int tx = tid & 15;   // item group
  const int ty = tid >> 4;   // row group
  const int rowbase = blockIdx.y * TILE_R;
  const int chunkbase = blockIdx.x * (TILE_I * SUPER);

  float best[8];
  int bidx[8];
#pragma unroll
  for (int i = 0; i < 8; i++) { best[i] = -3.4e38f; bidx[i] = 0x7fffffff; }

  for (int s = 0; s < SUPER; s++) {
    const int ib = chunkbase + s * TILE_I;
    if (ib >= M_ITEMS) break;

    float acc[8][8];
#pragma unroll
    for (int i = 0; i < 8; i++)
#pragma unroll
      for (int j = 0; j < 8; j++) acc[i][j] = 0.f;

    for (int ks = 0; ks < D_DIM; ks += KB) {
      __syncthreads();  // protect LDS from previous compute
      {
        const int rr = tid >> 3;         // 0..31
        const int kp = (tid & 7) * 4;    // 0..28
#pragma unroll
        for (int p = 0; p < 4; p++) {
          const int r = p * 32 + rr;     // 0..127
          float4 va = *(const float4*)&uf[(rowbase + r) * D_DIM + ks + kp];
          As[kp + 0][r] = va.x; As[kp + 1][r] = va.y;
          As[kp + 2][r] = va.z; As[kp + 3][r] = va.w;
          const int gi = ib + r;
          float4 vb;
          if (gi < M_ITEMS) vb = *(const float4*)&items[(long long)gi * D_DIM + ks + kp];
          else vb = make_float4(0.f, 0.f, 0.f, 0.f);
          Bs[kp + 0][r] = vb.x; Bs[kp + 1][r] = vb.y;
          Bs[kp + 2][r] = vb.z; Bs[kp + 3][r] = vb.w;
        }
      }
      __syncthreads();
#pragma unroll
      for (int k = 0; k < KB; k++) {
        const float4 a0 = *(const float4*)&As[k][ty * 8];
        const float4 a1 = *(const float4*)&As[k][ty * 8 + 4];
        const float4 b0 = *(const float4*)&Bs[k][tx * 8];
        const float4 b1 = *(const float4*)&Bs[k][tx * 8 + 4];
        const float av[8] = {a0.x, a0.y, a0.z, a0.w, a1.x, a1.y, a1.z, a1.w};
        const float bv[8] = {b0.x, b0.y, b0.z, b0.w, b1.x, b1.y, b1.z, b1.w};
#pragma unroll
        for (int i = 0; i < 8; i++)
#pragma unroll
          for (int j = 0; j < 8; j++)
            acc[i][j] = fmaf(av[i], bv[j], acc[i][j]);
      }
    }
    // per-tile epilogue: fold into running per-row best
#pragma unroll
    for (int i = 0; i < 8; i++) {
#pragma unroll
      for (int j = 0; j < 8; j++) {
        const int cidx = ib + tx * 8 + j;
        const float v = acc[i][j];
        if (cidx < M_ITEMS &&
            (v > best[i] || (v == best[i] && cidx < bidx[i]))) {
          best[i] = v; bidx[i] = cidx;
        }
      }
    }
  }

  // reduce across the 16 item-lanes (tx) sharing each row
#pragma unroll
  for (int i = 0; i < 8; i++) {
#pragma unroll
    for (int off = 8; off; off >>= 1) {
      float ov = __shfl_xor(best[i], off, 16);
      int oi = __shfl_xor(bidx[i], off, 16);
      if (ov > best[i] || (ov == best[i] && oi < bidx[i])) {
        best[i] = ov; bidx[i] = oi;
      }
    }
  }
  if (tx == 0) {
#pragma unroll
    for (int i = 0; i < 8; i++) {
      unsigned u = __float_as_uint(best[i]);
      u = (u & 0x80000000u) ? ~u : (u | 0x80000000u);
      unsigned long long key =
          ((unsigned long long)u << 32) | (unsigned)(~(unsigned)bidx[i]);
      atomicMax(&keys[rowbase + ty * 8 + i], key);
    }
  }
}

// ---------- kernel 6: unpack top1, gather, cosine sim per row ----------
__global__ void k_post(const unsigned long long* __restrict__ keys,
                       const int* __restrict__ uid,
                       const float* __restrict__ items,
                       float* __restrict__ out, float* __restrict__ sims,
                       float* __restrict__ rl) {
  int r = blockIdx.x * blockDim.x + threadIdx.x;
  if (r >= B_ROWS) return;
  unsigned long long key = keys[r];
  int idx = (int)(~(unsigned)(key & 0xFFFFFFFFull));
  out[r] = (float)idx;
  int orig = uid[2 * r + 1];
  const float* a = items + (long long)orig * D_DIM;
  const float* c = items + (long long)idx * D_DIM;
  float aa = 0.f, cc = 0.f, ac = 0.f;
#pragma unroll 4
  for (int d = 0; d < D_DIM; d++) {
    float x = a[d], y = c[d];
    aa = fmaf(x, x, aa);
    cc = fmaf(y, y, cc);
    ac = fmaf(x, y, ac);
  }
  float na = fmaxf(sqrtf(aa), COS_EPS_F);
  float nc = fmaxf(sqrtf(cc), COS_EPS_F);
  float sim = ac / (na * nc);
  sim = (sim + 1.f) * 0.5f;
  sims[r] = sim;
  rl[r] = fmaxf(sim - 0.5f, 0.f);
}

// ---------- kernel 7: deterministic final means ----------
__global__ void k_final(const float* __restrict__ sims, const float* __restrict__ rl,
                        float* __restrict__ out) {
  __shared__ float s1[256], s2[256];
  int t = threadIdx.x;
  float a = 0.f, b = 0.f;
  for (int r = t; r < B_ROWS; r += 256) { a += rl[r]; b += sims[r]; }
  s1[t] = a; s2[t] = b;
  __syncthreads();
  for (int off = 128; off; off >>= 1) {
    if (t < off) { s1[t] += s1[t + off]; s2[t] += s2[t + off]; }
    __syncthreads();
  }
  if (t == 0) {
    out[B_ROWS] = s1[0] / (float)B_ROWS;
    out[B_ROWS + 1] = s2[0] / (float)B_ROWS;
  }
}

extern "C" void kernel_launch(void* const* d_in, const int* in_sizes, int n_in,
                              void* d_out, int out_size, void* d_ws, size_t ws_size,
                              hipStream_t stream) {
  const float* item_feature = (const float*)d_in[0];
  const float* all_items    = (const float*)d_in[1];
  const int*   uid          = (const int*)d_in[2];
  const float* W            = (const float*)d_in[3];
  const float* bias         = (const float*)d_in[4];
  const float* gamma        = (const float*)d_in[5];
  const float* beta         = (const float*)d_in[6];
  float* out = (float*)d_out;

  float* h     = (float*)d_ws;            // 2048*128
  float* uf    = h + B_ROWS * D_DIM;      // 2048*128
  float* scale = uf + B_ROWS * D_DIM;     // 128
  float* shift = scale + D_DIM;           // 128
  unsigned long long* keys = (unsigned long long*)(shift + D_DIM);  // 2048 (8B-aligned offset)
  float* sims  = (float*)(keys + B_ROWS); // 2048
  float* rl    = sims + B_ROWS;           // 2048

  k_gemm1<<<B_ROWS, D_DIM, 0, stream>>>(item_feature, W, bias, h);
  k_bnstats<<<D_DIM, 256, 0, stream>>>(h, gamma, beta, scale, shift);
  k_norm<<<(B_ROWS * D_DIM) / 256, 256, 0, stream>>>(h, scale, shift, uf);
  k_init<<<(B_ROWS + 255) / 256, 256, 0, stream>>>(keys);
  dim3 sg((M_ITEMS + TILE_I * SUPER - 1) / (TILE_I * SUPER), B_ROWS / TILE_R);
  k_scores<<<sg, 256, 0, stream>>>(uf, all_items, keys);
  k_post<<<(B_ROWS + 255) / 256, 256, 0, stream>>>(keys, uid, all_items, out, sims, rl);
  k_final<<<1, 256, 0, stream>>>(sims, rl, out);
}

// Round 2
// 363.105 us; speedup vs baseline: 2.5362x; 2.5362x over previous
//
#include <hip/hip_runtime.h>
#include <stdint.h>

#define B_ROWS 2048
#define D2_DIM 256
#define D_DIM 128
#define M_ITEMS 100000
#define M_PAD 100352           // 196 * 512
#define BN_EPS_F 1e-5f
#define COS_EPS_F 1e-6f
#define LEAKY_F 0.01f
#define SUPER 4                // item tiles (128) per block

typedef __bf16 bf16x8 __attribute__((ext_vector_type(8)));
typedef float f32x4 __attribute__((ext_vector_type(4)));

// bf16 hi/lo split planes (device globals: avoids unknown ws_size; rebuilt every call)
__device__ unsigned short g_Aph[B_ROWS * D_DIM];
__device__ unsigned short g_Apl[B_ROWS * D_DIM];
__device__ unsigned short g_Bph[M_PAD * D_DIM];
__device__ unsigned short g_Bpl[M_PAD * D_DIM];

__device__ __forceinline__ unsigned bf16_rne(float f) {
  unsigned u = __float_as_uint(f);
  return (u + 0x7fffu + ((u >> 16) & 1u)) >> 16;
}
__device__ __forceinline__ void split_bf16(float v, unsigned short& hi, unsigned short& lo) {
  unsigned h = bf16_rne(v);
  float hf = __uint_as_float(h << 16);
  unsigned l = bf16_rne(v - hf);   // v - hf is exact in f32
  hi = (unsigned short)h; lo = (unsigned short)l;
}
__device__ __forceinline__ void gload16(const void* g, void* l) {
  __builtin_amdgcn_global_load_lds(
      (const __attribute__((address_space(1))) void*)g,
      (__attribute__((address_space(3))) void*)l, 16, 0, 0);
}

// ---------- kernel 1: h = item_feature @ W + b ----------
__global__ void k_gemm1(const float* __restrict__ A, const float* __restrict__ W,
                        const float* __restrict__ bias, float* __restrict__ h) {
  __shared__ float arow[D2_DIM];
  const int r = blockIdx.x;
  const int c = threadIdx.x;  // 128
  arow[c] = A[r * D2_DIM + c];
  arow[c + 128] = A[r * D2_DIM + c + 128];
  __syncthreads();
  float acc = 0.f;
#pragma unroll 8
  for (int k = 0; k < D2_DIM; k++) acc = fmaf(arow[k], W[k * D_DIM + c], acc);
  h[r * D_DIM + c] = acc + bias[c];
}

// ---------- kernel 2: per-column mean/var -> scale/shift ----------
__global__ void k_bnstats(const float* __restrict__ h, const float* __restrict__ gamma,
                          const float* __restrict__ beta, float* __restrict__ scale,
                          float* __restrict__ shift) {
  const int c = blockIdx.x;
  const int t = threadIdx.x;  // 256
  double s = 0.0, sq = 0.0;
  for (int r = t; r < B_ROWS; r += 256) {
    double v = (double)h[r * D_DIM + c];
    s += v; sq += v * v;
  }
  __shared__ double ls[256], lq[256];
  ls[t] = s; lq[t] = sq;
  __syncthreads();
  for (int off = 128; off; off >>= 1) {
    if (t < off) { ls[t] += ls[t + off]; lq[t] += lq[t + off]; }
    __syncthreads();
  }
  if (t == 0) {
    double mean = ls[0] / (double)B_ROWS;
    double var = lq[0] / (double)B_ROWS - mean * mean;
    float sc = (float)((double)gamma[c] / sqrt(var + (double)BN_EPS_F));
    scale[c] = sc;
    shift[c] = beta[c] - (float)mean * sc;
  }
}

// ---------- kernel 3: uf = leaky(bn(h)) -> bf16 hi/lo planes ----------
__global__ void k_norm_split(const float* __restrict__ h, const float* __restrict__ scale,
                             const float* __restrict__ shift) {
  int i = blockIdx.x * 256 + threadIdx.x;
  if (i >= B_ROWS * D_DIM) return;
  int c = i & (D_DIM - 1);
  float v = fmaf(h[i], scale[c], shift[c]);
  v = v >= 0.f ? v : LEAKY_F * v;
  unsigned short hi, lo;
  split_bf16(v, hi, lo);
  g_Aph[i] = hi; g_Apl[i] = lo;
}

// ---------- kernel 4: all_items -> bf16 hi/lo planes (pad rows zeroed) ----------
__global__ void k_build_items(const float* __restrict__ items) {
  long long t = (long long)blockIdx.x * 256 + threadIdx.x;  // one float4 per thread
  long long base = t * 4;
  if (base >= (long long)M_PAD * D_DIM) return;
  float4 v;
  if (base < (long long)M_ITEMS * D_DIM) v = *(const float4*)&items[base];
  else v = make_float4(0.f, 0.f, 0.f, 0.f);
  ushort4 hv, lv;
  split_bf16(v.x, hv.x, lv.x);
  split_bf16(v.y, hv.y, lv.y);
  split_bf16(v.z, hv.z, lv.z);
  split_bf16(v.w, hv.w, lv.w);
  *(ushort4*)&g_Bph[base] = hv;
  *(ushort4*)&g_Bpl[base] = lv;
}

// ---------- kernel 5: init argmax keys ----------
__global__ void k_init(unsigned long long* __restrict__ keys) {
  int i = blockIdx.x * blockDim.x + threadIdx.x;
  if (i < B_ROWS) keys[i] = 0ull;
}

// ---------- kernel 6: MFMA scores (3-term bf16 split) + fused argmax ----------
// block: 128 rows x (SUPER*128) items, 4 waves (2x2), wave tile 64x64.
// LDS tiles [128][64] bf16, XOR-swizzled via pre-swizzled global source.
__launch_bounds__(256, 2)
__global__ void k_scores_mfma(unsigned long long* __restrict__ keys) {
  __shared__ __align__(16) char smem[65536];
  char* sAh = smem;
  char* sAl = smem + 16384;
  char* sBh = smem + 32768;
  char* sBl = smem + 49152;

  const int tid = threadIdx.x;
  const int l = tid & 63;
  const int w = tid >> 6;      // wave 0..3
  const int wm = w >> 1;       // row half
  const int wn = w & 1;        // item half
  const int rowbase = blockIdx.y * 128;
  const int chunk = blockIdx.x * (SUPER * 128);

  const int lrow = l & 15;     // fragment lane row/col
  const int lkg = l >> 4;      // k-group 0..3
  const int rxor = (lrow & 7) << 4;        // read-side swizzle (row&7)<<4

  // staging geometry: thread covers row 32p + (tid>>3), 16B slot (tid&7), swizzled
  const int srow0 = tid >> 3;              // 0..31  (= 8w + (l>>3))
  const int sslot = (((tid & 7) ^ (srow0 & 7)) * 8);  // element offset in row
  const int ldsoff = 16 * tid;             // per-p add 4096

  float bestv[16];
  int besti[16];
#pragma unroll
  for (int q = 0; q < 16; q++) { bestv[q] = -3.0e38f; besti[q] = 0x7fffffff; }

  for (int s = 0; s < SUPER; s++) {
    const int itembase = chunk + s * 128;
    f32x4 acc[4][4];
#pragma unroll
    for (int mi = 0; mi < 4; mi++)
#pragma unroll
      for (int ni = 0; ni < 4; ni++) acc[mi][ni] = (f32x4)(0.0f);

    for (int ks = 0; ks < D_DIM; ks += 64) {
      __syncthreads();
#pragma unroll
      for (int p = 0; p < 4; p++) {
        const int r = 32 * p + srow0;
        const size_t aoff = (size_t)(rowbase + r) * D_DIM + ks + sslot;
        const size_t boff = (size_t)(itembase + r) * D_DIM + ks + sslot;
        const int lo = 4096 * p + ldsoff;
        gload16(g_Aph + aoff, sAh + lo);
        gload16(g_Apl + aoff, sAl + lo);
        gload16(g_Bph + boff, sBh + lo);
        gload16(g_Bpl + boff, sBl + lo);
      }
      __syncthreads();
#pragma unroll
      for (int kk = 0; kk < 2; kk++) {
        const int kbyte = kk * 64 + lkg * 16;
        bf16x8 ah[4], al[4], bh[4], bl[4];
#pragma unroll
        for (int mi = 0; mi < 4; mi++) {
          const int row = wm * 64 + mi * 16 + lrow;
          const int off = row * 128 + (kbyte ^ rxor);
          ah[mi] = *(const bf16x8*)(sAh + off);
          al[mi] = *(const bf16x8*)(sAl + off);
        }
#pragma unroll
        for (int ni = 0; ni < 4; ni++) {
          const int itm = wn * 64 + ni * 16 + lrow;
          const int off = itm * 128 + (kbyte ^ rxor);
          bh[ni] = *(const bf16x8*)(sBh + off);
          bl[ni] = *(const bf16x8*)(sBl + off);
        }
#pragma unroll
        for (int mi = 0; mi < 4; mi++)
#pragma unroll
          for (int ni = 0; ni < 4; ni++) {
            f32x4 c = acc[mi][ni];
            c = __builtin_amdgcn_mfma_f32_16x16x32_bf16(ah[mi], bh[ni], c, 0, 0, 0);
            c = __builtin_amdgcn_mfma_f32_16x16x32_bf16(al[mi], bh[ni], c, 0, 0, 0);
            c = __builtin_amdgcn_mfma_f32_16x16x32_bf16(ah[mi], bl[ni], c, 0, 0, 0);
            acc[mi][ni] = c;
          }
      }
    }
    // fold this item tile into per-lane running best (strict > keeps lowest idx)
#pragma unroll
    for (int mi = 0; mi < 4; mi++) {
#pragma unroll
      for (int ni = 0; ni < 4; ni++) {
        const int col = itembase + wn * 64 + ni * 16 + lrow;
        const bool valid = col < M_ITEMS;
#pragma unroll
        for (int reg = 0; reg < 4; reg++) {
          const float v = acc[mi][ni][reg];
          const int q = mi * 4 + reg;
          if (valid && v > bestv[q]) { bestv[q] = v; besti[q] = col; }
        }
      }
    }
  }

  // cross-lane reduce over the 16 cols held per lane-group, then atomicMax
#pragma unroll
  for (int q = 0; q < 16; q++) {
    float v = bestv[q];
    int bi = besti[q];
#pragma unroll
    for (int off = 1; off < 16; off <<= 1) {
      float ov = __shfl_xor(v, off, 16);
      int oi = __shfl_xor(bi, off, 16);
      if (ov > v || (ov == v && oi < bi)) { v = ov; bi = oi; }
    }
    if (lrow == 0) {
      const int row = rowbase + wm * 64 + (q >> 2) * 16 + lkg * 4 + (q & 3);
      unsigned u = __float_as_uint(v);
      u = (u & 0x80000000u) ? ~u : (u | 0x80000000u);
      unsigned long long key =
          ((unsigned long long)u << 32) | (unsigned)(~(unsigned)bi);
      atomicMax(&keys[row], key);
    }
  }
}

// ---------- kernel 7: unpack top1, gather, cosine sim ----------
__global__ void k_post(const unsigned long long* __restrict__ keys,
                       const int* __restrict__ uid,
                       const float* __restrict__ items,
                       float* __restrict__ out, float* __restrict__ sims,
                       float* __restrict__ rl) {
  int r = blockIdx.x * blockDim.x + threadIdx.x;
  if (r >= B_ROWS) return;
  unsigned long long key = keys[r];
  int idx = (int)(~(unsigned)(key & 0xFFFFFFFFull));
  out[r] = (float)idx;
  int orig = uid[2 * r + 1];
  const float* a = items + (long long)orig * D_DIM;
  const float* c = items + (long long)idx * D_DIM;
  float aa = 0.f, cc = 0.f, ac = 0.f;
#pragma unroll 4
  for (int d = 0; d < D_DIM; d++) {
    float x = a[d], y = c[d];
    aa = fmaf(x, x, aa);
    cc = fmaf(y, y, cc);
    ac = fmaf(x, y, ac);
  }
  float na = fmaxf(sqrtf(aa), COS_EPS_F);
  float nc = fmaxf(sqrtf(cc), COS_EPS_F);
  float sim = ac / (na * nc);
  sim = (sim + 1.f) * 0.5f;
  sims[r] = sim;
  rl[r] = fmaxf(sim - 0.5f, 0.f);
}

// ---------- kernel 8: deterministic final means ----------
__global__ void k_final(const float* __restrict__ sims, const float* __restrict__ rl,
                        float* __restrict__ out) {
  __shared__ float s1[256], s2[256];
  int t = threadIdx.x;
  float a = 0.f, b = 0.f;
  for (int r = t; r < B_ROWS; r += 256) { a += rl[r]; b += sims[r]; }
  s1[t] = a; s2[t] = b;
  __syncthreads();
  for (int off = 128; off; off >>= 1) {
    if (t < off) { s1[t] += s1[t + off]; s2[t] += s2[t + off]; }
    __syncthreads();
  }
  if (t == 0) {
    out[B_ROWS] = s1[0] / (float)B_ROWS;
    out[B_ROWS + 1] = s2[0] / (float)B_ROWS;
  }
}

extern "C" void kernel_launch(void* const* d_in, const int* in_sizes, int n_in,
                              void* d_out, int out_size, void* d_ws, size_t ws_size,
                              hipStream_t stream) {
  const float* item_feature = (const float*)d_in[0];
  const float* all_items    = (const float*)d_in[1];
  const int*   uid          = (const int*)d_in[2];
  const float* W            = (const float*)d_in[3];
  const float* bias         = (const float*)d_in[4];
  const float* gamma        = (const float*)d_in[5];
  const float* beta         = (const float*)d_in[6];
  float* out = (float*)d_out;

  float* h     = (float*)d_ws;             // 2048*128
  float* scale = h + B_ROWS * D_DIM;       // 128
  float* shift = scale + D_DIM;            // 128
  unsigned long long* keys = (unsigned long long*)(shift + D_DIM);  // 2048
  float* sims  = (float*)(keys + B_ROWS);  // 2048
  float* rl    = sims + B_ROWS;            // 2048

  k_gemm1<<<B_ROWS, D_DIM, 0, stream>>>(item_feature, W, bias, h);
  k_bnstats<<<D_DIM, 256, 0, stream>>>(h, gamma, beta, scale, shift);
  k_norm_split<<<(B_ROWS * D_DIM + 255) / 256, 256, 0, stream>>>(h, scale, shift);
  k_build_items<<<(M_PAD * D_DIM / 4 + 255) / 256, 256, 0, stream>>>(all_items);
  k_init<<<(B_ROWS + 255) / 256, 256, 0, stream>>>(keys);
  dim3 sg(M_PAD / (SUPER * 128), B_ROWS / 128);
  k_scores_mfma<<<sg, 256, 0, stream>>>(keys);
  k_post<<<(B_ROWS + 255) / 256, 256, 0, stream>>>(keys, uid, all_items, out, sims, rl);
  k_final<<<1, 256, 0, stream>>>(sims, rl, out);
}